// Round 1
// baseline (154.632 us; speedup 1.0000x reference)
//
#include <hip/hip_runtime.h>
#include <hip/hip_bf16.h>
#include <cstdint>
#include <cstddef>

// B=4, C=128, L=4096, H=4 (hd=32), GROUPS=32, EPS=1e-5
// gn_stats (affine + weight cvt) -> MFMA qkv (gn inline; Qt/Kt bf16 [l][32], Vb fp16 [32][l])
// -> MFMA flash attention, S-SPLIT x2 (this round): grid (L/128, 2, B*H) = 1024 blocks
//    (4 blocks/CU instead of 2 -> double occupancy). No running max is used, so the two
//    s-halves produce raw partial sums (O_num f32, l f32) that combine by plain addition.
// -> MFMA proj (+bias +raw-x residual) with inline partial-combine:
//    B-fragment = (P0 + P1) * 1/(l0+l1) packed to bf16 on the fly.
//
// ws layout (bytes):
//   wq_b  bf16 49,152    @ 0
//   wp_b  bf16 16,384    @ 98,304
//   bp_f  f32  128       @ 131,072
//   gn_ab f32x2 512      @ 131,584
//   lsum  f32  524,288   @ 139,264     [sh][b][h][l]
//   Qt    bf16 2,097,152 @ 8,388,608   [b*H+h][l][32]
//   Kt    bf16 2,097,152 @ 12,582,912  [b*H+h][l][32]
//   Vb    fp16 2,097,152 @ 16,777,216  [b*H+h][32][l]
//   Pp    f32  16,777,216 @ 20,971,520 [sh][b][l][128]  (O numerator partials)
//   total 37,748,736

#define B_ 4
#define C_ 128
#define L_ 4096
#define H_ 4
#define HD_ 32
#define NG_ 32
#define CPG_ 4
#define EPS_ 1e-5f
#define QKSCALE_ 0.5050097650430367f  // 32^(-1/4) * sqrt(log2 e)

typedef __attribute__((ext_vector_type(8))) short bf16x8;
typedef __attribute__((ext_vector_type(8))) unsigned short u16x8;
typedef __attribute__((ext_vector_type(4))) float f32x4;
typedef __attribute__((ext_vector_type(2))) _Float16 f16x2;
typedef __attribute__((ext_vector_type(4))) _Float16 f16x4;

#if __has_builtin(__builtin_amdgcn_exp2f)
#define EXP2F(x) __builtin_amdgcn_exp2f(x)
#else
#define EXP2F(x) exp2f(x)
#endif

// __has_builtin(amdgcn) is FALSE in the host pass but raw calls parse in device code.
// Never #error here (R11 lesson).
#define MFMA_PV(a, b, c) __builtin_amdgcn_mfma_f32_16x16x16f16((a), (b), (c), 0, 0, 0)

__device__ __forceinline__ float bu2f(unsigned short u) {
  return __builtin_bit_cast(float, (unsigned int)(((unsigned int)u) << 16));
}
__device__ __forceinline__ unsigned short f2bu(float f) {
  unsigned int u = __builtin_bit_cast(unsigned int, f);
  unsigned int r = (u + 0x7fffu + ((u >> 16) & 1u)) >> 16;  // RNE
  return (unsigned short)r;
}
__device__ __forceinline__ float4 u42f4(ushort4 u) {
  return make_float4(bu2f(u.x), bu2f(u.y), bu2f(u.z), bu2f(u.w));
}
__device__ __forceinline__ unsigned int pkbf(float a, float b) {
  return (unsigned int)f2bu(a) | ((unsigned int)f2bu(b) << 16);
}
__device__ __forceinline__ f16x2 pkhf2(float a, float b) {
#if __has_builtin(__builtin_amdgcn_cvt_pkrtz)
  return __builtin_bit_cast(f16x2, __builtin_amdgcn_cvt_pkrtz(a, b));
#else
  f16x2 r;
  r[0] = (_Float16)a;
  r[1] = (_Float16)b;
  return r;
#endif
}
__device__ __forceinline__ unsigned int pkhf(float a, float b) {
  return __builtin_bit_cast(unsigned int, pkhf2(a, b));
}

// fp32-vs-bf16 detection via wave-0 ballot — proven R9.
__device__ __forceinline__ bool detect_fast(const ushort* x) {
  __shared__ int flag_s;
  int t = threadIdx.x;
  if (t < 64) {
    int e = (x[t] >> 7) & 0xFF;
    unsigned long long m = __ballot((e < 64) || (e > 192));
    if (t == 0) flag_s = (__popcll(m) > 4) ? 1 : 0;
  }
  __syncthreads();
  return flag_s != 0;
}

__device__ __forceinline__ float4 ldx4(const void* x, size_t idx, bool f32) {
  if (f32) return *((const float4*)x + (idx >> 2));
  ushort4 u = *((const ushort4*)x + (idx >> 2));
  return u42f4(u);
}

// ---------------------------------------------------------------- GN stats + weight cvt
// Unchanged from R13.
__global__ __launch_bounds__(256) void gn_stats(const void* __restrict__ x,
                                                const void* __restrict__ wq,
                                                const void* __restrict__ wp,
                                                const void* __restrict__ bp,
                                                const void* __restrict__ gm,
                                                const void* __restrict__ bt,
                                                ushort* __restrict__ wq_b,
                                                ushort* __restrict__ wp_b,
                                                float* __restrict__ bp_f,
                                                float2* __restrict__ gn_ab) {
  bool f32 = detect_fast((const ushort*)x);
  int blk = blockIdx.x;
  int t = threadIdx.x;

  if (blk >= 128) {
    int i0 = ((blk - 128) * 256 + t) * 8;
#pragma unroll
    for (int k = 0; k < 8; ++k) {
      int i = i0 + k;
      if (i >= 65664) break;
      if (i < 49152) {
        wq_b[i] = f32 ? f2bu(((const float*)wq)[i]) : ((const ushort*)wq)[i];
      } else if (i < 65536) {
        int off = i - 49152;
        wp_b[off] = f32 ? f2bu(((const float*)wp)[off]) : ((const ushort*)wp)[off];
      } else {
        int off = i - 65536;
        bp_f[off] = f32 ? ((const float*)bp)[off] : bu2f(((const ushort*)bp)[off]);
      }
    }
    return;
  }

  int b = blk >> 5, g = blk & 31;
  size_t base = ((size_t)b * C_ + (size_t)g * CPG_) * L_;

  float s = 0.f, ss = 0.f;
#pragma unroll
  for (int i = 0; i < 16; ++i) {
    size_t e = base + i * 1024 + t * 4;
    float4 f = ldx4(x, e, f32);
    s += f.x + f.y + f.z + f.w;
    ss += f.x * f.x + f.y * f.y + f.z * f.z + f.w * f.w;
  }
#pragma unroll
  for (int m = 32; m >= 1; m >>= 1) {
    s += __shfl_xor(s, m, 64);
    ss += __shfl_xor(ss, m, 64);
  }
  __shared__ float red[4][2];
  int wv = t >> 6;
  if ((t & 63) == 0) { red[wv][0] = s; red[wv][1] = ss; }
  __syncthreads();
  float ts = red[0][0] + red[1][0] + red[2][0] + red[3][0];
  float tss = red[0][1] + red[1][1] + red[2][1] + red[3][1];
  float mu = ts * (1.0f / 16384.0f);
  float var = tss * (1.0f / 16384.0f) - mu * mu;
  float rs = rsqrtf(var + EPS_);

  if (t < CPG_) {
    int gi = g * CPG_ + t;
    float ga = f32 ? ((const float*)gm)[gi] : bu2f(((const ushort*)gm)[gi]);
    float be = f32 ? ((const float*)bt)[gi] : bu2f(((const ushort*)bt)[gi]);
    gn_ab[b * C_ + gi] = make_float2(ga * rs, be - mu * ga * rs);
  }
}

// ---------------------------------------------------------------- QKV GEMM (MFMA, gn inline)
// Unchanged from R13.
__global__ __launch_bounds__(256) void qkv_kernel(const ushort* __restrict__ wq_b,
                                                  const void* __restrict__ x,
                                                  const float2* __restrict__ gn_ab,
                                                  ushort* __restrict__ Qt,
                                                  ushort* __restrict__ Kt,
                                                  ushort* __restrict__ Vb) {
  bool f32 = detect_fast((const ushort*)x);
  __shared__ alignas(16) ushort Hs[64][136];
  __shared__ alignas(16) float Ls[64][69];

  int lx = blockIdx.x, oz = blockIdx.y, b = blockIdx.z;
  int t = threadIdx.x;
  int w = t >> 6, lane = t & 63, l16 = lane & 15, q = lane >> 4, q8 = q * 8;

  {
    int u = t & 63, lh = (t >> 6) * 16;
    int c0 = 2 * u;
    float2 ab0 = gn_ab[b * C_ + c0];
    float2 ab1 = gn_ab[b * C_ + c0 + 1];
    size_t xo = ((size_t)b * C_ + c0) * L_ + (size_t)lx * 64 + lh;
#pragma unroll
    for (int j = 0; j < 4; ++j) {
      float4 f0 = ldx4(x, xo + j * 4, f32);
      float4 f1 = ldx4(x, xo + L_ + j * 4, f32);
      float n0[4] = {f0.x * ab0.x + ab0.y, f0.y * ab0.x + ab0.y,
                     f0.z * ab0.x + ab0.y, f0.w * ab0.x + ab0.y};
      float n1[4] = {f1.x * ab1.x + ab1.y, f1.y * ab1.x + ab1.y,
                     f1.z * ab1.x + ab1.y, f1.w * ab1.x + ab1.y};
#pragma unroll
      for (int k = 0; k < 4; ++k)
        *(unsigned int*)&Hs[lh + j * 4 + k][c0] = pkbf(n0[k], n1[k]);
    }
  }
  __syncthreads();

  for (int j = 0; j < 2; ++j) {
    int oy = oz * 2 + j;
    const ushort* wg = wq_b + (size_t)(oy * 64 + w * 16 + l16) * C_;

    f32x4 acc[4] = {{0.f, 0.f, 0.f, 0.f}, {0.f, 0.f, 0.f, 0.f},
                    {0.f, 0.f, 0.f, 0.f}, {0.f, 0.f, 0.f, 0.f}};
#pragma unroll
    for (int kc = 0; kc < 4; ++kc) {
      bf16x8 aw = *(const bf16x8*)(wg + kc * 32 + q8);
#pragma unroll
      for (int nb = 0; nb < 4; ++nb) {
        bf16x8 bh = *(const bf16x8*)&Hs[nb * 16 + l16][kc * 32 + q8];
        acc[nb] = __builtin_amdgcn_mfma_f32_16x16x32_bf16(aw, bh, acc[nb], 0, 0, 0);
      }
    }
    __syncthreads();
#pragma unroll
    for (int nb = 0; nb < 4; ++nb)
#pragma unroll
      for (int r = 0; r < 4; ++r)
        Ls[nb * 16 + l16][w * 16 + 4 * q + r] = acc[nb][r];
    __syncthreads();

#pragma unroll
    for (int hhalf = 0; hhalf < 2; ++hhalf) {
      int hh = oy * 2 + hhalf;
      int type = hh % 3, head = hh / 3;
      size_t bh = (size_t)b * H_ + head;
      if (type == 2) {
        int c_loc = t >> 3, l8 = (t & 7) * 8;
        float v[8];
#pragma unroll
        for (int jj = 0; jj < 8; ++jj) v[jj] = Ls[l8 + jj][hhalf * 32 + c_loc];
        uint4 u;
        u.x = pkhf(v[0], v[1]);
        u.y = pkhf(v[2], v[3]);
        u.z = pkhf(v[4], v[5]);
        u.w = pkhf(v[6], v[7]);
        *(uint4*)(Vb + (bh * 32 + c_loc) * L_ + (size_t)lx * 64 + l8) = u;
      } else {
        ushort* dst = type ? Kt : Qt;
        int l = t >> 2, seg = (t & 3) * 8;
        const float* src = &Ls[l][hhalf * 32 + seg];
        uint4 u;
        u.x = pkbf(src[0] * QKSCALE_, src[1] * QKSCALE_);
        u.y = pkbf(src[2] * QKSCALE_, src[3] * QKSCALE_);
        u.z = pkbf(src[4] * QKSCALE_, src[5] * QKSCALE_);
        u.w = pkbf(src[6] * QKSCALE_, src[7] * QKSCALE_);
        *(uint4*)(dst + ((bh * L_) + lx * 64 + l) * 32 + seg) = u;
      }
    }
  }
}

// ---------------------------------------------------------------- MFMA flash attention
// S-SPLIT: blockIdx.y selects s-half (2048 s-positions, 16 iters). No running max ->
// partials combine by plain addition in proj. Per block: 128-query tiles, 128 s per
// barrier, register-P PV 16x16x16 f16, l via ones-MFMA.
// Outputs raw f32 partials: Pp[sh][b][l][128] (O numerator), lsum[sh][b][h][l].
__global__ __launch_bounds__(256) void attn_kernel(const ushort* __restrict__ Qt,
                                                   const ushort* __restrict__ Kt,
                                                   const ushort* __restrict__ Vb,
                                                   float* __restrict__ Pp,
                                                   float* __restrict__ lsum) {
  __shared__ alignas(16) ushort Ks[2][4096];     // two frag-linear 64x32 K tiles
  __shared__ alignas(16) ushort Vs[2][32][136];  // [c][s0..127] fp16

  int t = threadIdx.x;
  int w = t >> 6, lane = t & 63, l16 = lane & 15, q = lane >> 4;
  int tq0 = blockIdx.x * 128;
  int sh = blockIdx.y;
  int bh = blockIdx.z;
  int b = bh >> 2, head = bh & 3;
  const ushort* Qg = Qt + ((size_t)bh * L_ + tq0) * 32;
  const ushort* Kg = Kt + ((size_t)bh * L_ + (size_t)sh * 2048) * 32;
  const ushort* Vg = Vb + (size_t)bh * 32 * L_ + (size_t)sh * 2048;

  int krow = (t & 15) | ((t >> 6) << 4);
  int kq8 = ((t >> 4) & 3) * 8;
  const ushort* kgp = Kg + (size_t)krow * 32 + kq8;
  int vc = t >> 3, vsl = (t & 7) * 8;
  const ushort* vgp = Vg + (size_t)vc * L_ + vsl;
  int trow = w * 16 + l16;
  int q8 = q * 8, q4 = q * 4;

  bf16x8 qfrag0 = *(const bf16x8*)(Qg + (size_t)trow * 32 + q8);
  bf16x8 qfrag1 = *(const bf16x8*)(Qg + (size_t)(64 + trow) * 32 + q8);
  f16x4 ones;
#pragma unroll
  for (int i = 0; i < 4; ++i) ones[i] = (_Float16)1.0f;

  // prologue: stage both halves of tile 0
  *(uint4*)&Ks[0][t * 8] = *(const uint4*)kgp;
  *(uint4*)&Ks[0][2048 + t * 8] = *(const uint4*)(kgp + 2048);
  *(uint4*)&Vs[0][vc][vsl] = *(const uint4*)vgp;
  *(uint4*)&Vs[0][vc][64 + vsl] = *(const uint4*)(vgp + 64);
  __syncthreads();

  f32x4 aA0 = {0.f, 0.f, 0.f, 0.f}, aB0 = {0.f, 0.f, 0.f, 0.f};
  f32x4 aA1 = {0.f, 0.f, 0.f, 0.f}, aB1 = {0.f, 0.f, 0.f, 0.f};
  f32x4 aL0 = {0.f, 0.f, 0.f, 0.f}, aL1 = {0.f, 0.f, 0.f, 0.f};
  const ushort* kg_n = kgp + 4096;
  const ushort* vg_n = vgp + 128;

#pragma unroll 2
  for (int it = 0; it < 16; ++it) {
    int bc = it & 1;
    if (it < 15) {
      *(uint4*)&Ks[bc ^ 1][t * 8] = *(const uint4*)kg_n;
      *(uint4*)&Ks[bc ^ 1][2048 + t * 8] = *(const uint4*)(kg_n + 2048);
      *(uint4*)&Vs[bc ^ 1][vc][vsl] = *(const uint4*)vg_n;
      *(uint4*)&Vs[bc ^ 1][vc][64 + vsl] = *(const uint4*)(vg_n + 64);
      kg_n += 4096;
      vg_n += 128;
    }

#pragma unroll
    for (int hh2 = 0; hh2 < 2; ++hh2) {
      const ushort* kf = &Ks[bc][hh2 * 2048 + lane * 8];
      bf16x8 ak0 = *(const bf16x8*)(kf);
      bf16x8 ak1 = *(const bf16x8*)(kf + 512);
      bf16x8 ak2 = *(const bf16x8*)(kf + 1024);
      bf16x8 ak3 = *(const bf16x8*)(kf + 1536);
      f32x4 z = {0.f, 0.f, 0.f, 0.f};
      f32x4 sf0[4], sf1[4];
      sf0[0] = __builtin_amdgcn_mfma_f32_16x16x32_bf16(ak0, qfrag0, z, 0, 0, 0);
      sf0[1] = __builtin_amdgcn_mfma_f32_16x16x32_bf16(ak1, qfrag0, z, 0, 0, 0);
      sf0[2] = __builtin_amdgcn_mfma_f32_16x16x32_bf16(ak2, qfrag0, z, 0, 0, 0);
      sf0[3] = __builtin_amdgcn_mfma_f32_16x16x32_bf16(ak3, qfrag0, z, 0, 0, 0);
      sf1[0] = __builtin_amdgcn_mfma_f32_16x16x32_bf16(ak0, qfrag1, z, 0, 0, 0);
      sf1[1] = __builtin_amdgcn_mfma_f32_16x16x32_bf16(ak1, qfrag1, z, 0, 0, 0);
      sf1[2] = __builtin_amdgcn_mfma_f32_16x16x32_bf16(ak2, qfrag1, z, 0, 0, 0);
      sf1[3] = __builtin_amdgcn_mfma_f32_16x16x32_bf16(ak3, qfrag1, z, 0, 0, 0);

#pragma unroll
      for (int n = 0; n < 4; ++n) {
        f16x4 va0 = *(const f16x4*)&Vs[bc][l16][hh2 * 64 + n * 16 + q4];
        f16x4 va1 = *(const f16x4*)&Vs[bc][16 + l16][hh2 * 64 + n * 16 + q4];
        {  // q-tile 0
          float p0 = EXP2F(sf0[n][0]);
          float p1 = EXP2F(sf0[n][1]);
          float p2 = EXP2F(sf0[n][2]);
          float p3 = EXP2F(sf0[n][3]);
          f16x2 e01 = pkhf2(p0, p1);
          f16x2 e23 = pkhf2(p2, p3);
          f16x4 pb = __builtin_shufflevector(e01, e23, 0, 1, 2, 3);
          aA0 = MFMA_PV(va0, pb, aA0);
          aB0 = MFMA_PV(va1, pb, aB0);
          aL0 = MFMA_PV(ones, pb, aL0);
        }
        {  // q-tile 1
          float p0 = EXP2F(sf1[n][0]);
          float p1 = EXP2F(sf1[n][1]);
          float p2 = EXP2F(sf1[n][2]);
          float p3 = EXP2F(sf1[n][3]);
          f16x2 e01 = pkhf2(p0, p1);
          f16x2 e23 = pkhf2(p2, p3);
          f16x4 pb = __builtin_shufflevector(e01, e23, 0, 1, 2, 3);
          aA1 = MFMA_PV(va0, pb, aA1);
          aB1 = MFMA_PV(va1, pb, aB1);
          aL1 = MFMA_PV(ones, pb, aL1);
        }
      }
    }
    __syncthreads();
  }

  // l partial: aL rows are all identical = sum_s P[s][q]; q-group 0 writes.
  {
    float* lp = lsum + ((size_t)sh * B_ * H_ + bh) * L_ + tq0;
    if (q == 0) {
      lp[trow] = aL0[0];
      lp[64 + trow] = aL1[0];
    }
  }

  // O numerator partial (raw f32, no normalization): transpose via LDS overlay on Ks,
  // two passes of 64 queries x 32 c f32 (64*36*4 = 9216 B <= 16384 B).
  float* Pb = Pp + (size_t)sh * ((size_t)B_ * L_ * C_) +
              ((size_t)b * L_ + tq0) * C_ + head * 32;
  float* Ep = (float*)&Ks[0][0];
#pragma unroll
  for (int p = 0; p < 2; ++p) {
    f32x4 vA = p ? aA1 : aA0;
    f32x4 vB = p ? aB1 : aB0;
#pragma unroll
    for (int r = 0; r < 4; ++r) {
      Ep[trow * 36 + q4 + r] = vA[r];
      Ep[trow * 36 + 16 + q4 + r] = vB[r];
    }
    __syncthreads();
    {
      int row = t >> 2, seg = (t & 3) * 8;
      const float* sp = &Ep[row * 36 + seg];
      float4 r0 = *(const float4*)sp;
      float4 r1 = *(const float4*)(sp + 4);
      float* dst = Pb + (size_t)(p * 64 + row) * C_ + seg;
      *(float4*)dst = r0;
      *(float4*)(dst + 4) = r1;
    }
    __syncthreads();
  }
}

// ---------------------------------------------------------------- Proj + bias + residual
// Combines the two attention s-half partials inline: B-fragment = (P0+P1) * 1/(l0+l1),
// packed to bf16 on the fly. Epilogue (bias + residual + dtype) unchanged.
__global__ __launch_bounds__(256) void proj_kernel(const ushort* __restrict__ wp_b,
                                                   const float* __restrict__ bias,
                                                   const void* __restrict__ x,
                                                   const float* __restrict__ Pp,
                                                   const float* __restrict__ lsum,
                                                   void* __restrict__ out) {
  bool f32 = detect_fast((const ushort*)x);
  __shared__ alignas(16) float Ls[64][37];

  int lx = blockIdx.x, oy = blockIdx.y, b = blockIdx.z;
  int t = threadIdx.x;
  int w = t >> 6, lane = t & 63, l16 = lane & 15, q = lane >> 4, q8 = q * 8;

  const ushort* wg = wp_b + (size_t)(oy * 64 + w * 16 + l16) * C_;
  const float* og0 = Pp + ((size_t)b * L_ + (size_t)lx * 32) * C_;
  const size_t HALF = (size_t)B_ * L_ * C_;
  const size_t LHALF = (size_t)B_ * H_ * L_;

  // per-thread inverse denominators for rows nb*16+l16, head kc
  float inv[2][4];
#pragma unroll
  for (int nb = 0; nb < 2; ++nb)
#pragma unroll
    for (int kc = 0; kc < 4; ++kc) {
      size_t li = ((size_t)b * H_ + kc) * L_ + (size_t)lx * 32 + nb * 16 + l16;
      inv[nb][kc] = 1.0f / (lsum[li] + lsum[LHALF + li]);
    }

  f32x4 acc[2] = {{0.f, 0.f, 0.f, 0.f}, {0.f, 0.f, 0.f, 0.f}};
#pragma unroll
  for (int kc = 0; kc < 4; ++kc) {
    bf16x8 aw = *(const bf16x8*)(wg + kc * 32 + q8);
#pragma unroll
    for (int nb = 0; nb < 2; ++nb) {
      const float* pf = og0 + (size_t)(nb * 16 + l16) * C_ + kc * 32 + q8;
      float4 u0 = *(const float4*)pf;
      float4 u1 = *(const float4*)(pf + 4);
      float4 v0 = *(const float4*)(pf + HALF);
      float4 v1 = *(const float4*)(pf + HALF + 4);
      float s = inv[nb][kc];
      uint4 pk;
      pk.x = pkbf((u0.x + v0.x) * s, (u0.y + v0.y) * s);
      pk.y = pkbf((u0.z + v0.z) * s, (u0.w + v0.w) * s);
      pk.z = pkbf((u1.x + v1.x) * s, (u1.y + v1.y) * s);
      pk.w = pkbf((u1.z + v1.z) * s, (u1.w + v1.w) * s);
      bf16x8 bo = __builtin_bit_cast(bf16x8, pk);
      acc[nb] = __builtin_amdgcn_mfma_f32_16x16x32_bf16(aw, bo, acc[nb], 0, 0, 0);
    }
  }
#pragma unroll
  for (int nb = 0; nb < 2; ++nb)
#pragma unroll
    for (int r = 0; r < 4; ++r)
      Ls[w * 16 + 4 * q + r][nb * 16 + l16] = acc[nb][r];
  __syncthreads();

  {
    int o_loc = t >> 2, ls0 = (t & 3) * 8;
    float bv = bias[oy * 64 + o_loc];
    size_t off = ((size_t)b * C_ + oy * 64 + o_loc) * L_ + (size_t)lx * 32 + ls0;
#pragma unroll
    for (int jj = 0; jj < 2; ++jj) {
      float4 xf = ldx4(x, off + jj * 4, f32);
      const float* sp = &Ls[o_loc][ls0 + jj * 4];
      float4 r = make_float4(sp[0] + bv + xf.x, sp[1] + bv + xf.y,
                             sp[2] + bv + xf.z, sp[3] + bv + xf.w);
      if (f32) {
        *(float4*)((float*)out + off + jj * 4) = r;
      } else {
        *(ushort4*)((ushort*)out + off + jj * 4) =
            make_ushort4(f2bu(r.x), f2bu(r.y), f2bu(r.z), f2bu(r.w));
      }
    }
  }
}

// ---------------------------------------------------------------- launch
extern "C" void kernel_launch(void* const* d_in, const int* in_sizes, int n_in,
                              void* d_out, int out_size, void* d_ws, size_t ws_size,
                              hipStream_t stream) {
  const void* x      = d_in[0];
  const void* w_qkv  = d_in[1];
  const void* w_proj = d_in[2];
  const void* b_proj = d_in[3];
  const void* gamma  = d_in[4];
  const void* beta   = d_in[5];

  char* wsb = (char*)d_ws;
  ushort* wq_b  = (ushort*)(wsb + 0);
  ushort* wp_b  = (ushort*)(wsb + 98304);
  float*  bp_f  = (float*)(wsb + 131072);
  float2* gn_ab = (float2*)(wsb + 131584);
  float*  lsum  = (float*)(wsb + 139264);    // 2*B*H*L f32 = 524,288 B
  ushort* Qt    = (ushort*)(wsb + 8388608);
  ushort* Kt    = (ushort*)(wsb + 12582912);
  ushort* Vb    = (ushort*)(wsb + 16777216);  // fp16
  float*  Pp    = (float*)(wsb + 20971520);   // 2 * B*L*C f32 = 16,777,216 B

  gn_stats<<<dim3(161), dim3(256), 0, stream>>>(x, w_qkv, w_proj, b_proj, gamma, beta,
                                                wq_b, wp_b, bp_f, gn_ab);
  qkv_kernel<<<dim3(L_ / 64, 3, B_), dim3(256), 0, stream>>>(wq_b, x, gn_ab, Qt, Kt, Vb);
  attn_kernel<<<dim3(L_ / 128, 2, B_ * H_), dim3(256), 0, stream>>>(Qt, Kt, Vb, Pp, lsum);
  proj_kernel<<<dim3(L_ / 32, C_ / 64, B_), dim3(256), 0, stream>>>(wp_b, bp_f, x, Pp, lsum, d_out);
}

// Round 2
// 144.311 us; speedup vs baseline: 1.0715x; 1.0715x over previous
//
#include <hip/hip_runtime.h>
#include <hip/hip_bf16.h>
#include <cstdint>
#include <cstddef>

// B=4, C=128, L=4096, H=4 (hd=32), GROUPS=32, EPS=1e-5
// gn_stats (affine + weight cvt) -> MFMA qkv (gn inline; Qt/Kt bf16 [l][32], Vb fp16 [32][l])
// -> MFMA flash attention v3 (this round):
//      512-thread blocks, 8 waves x 1 q-frag (16 rows each), 128-q block, 128 s/iter.
//      K/V staged via global_load_lds width-16 (async DMA, no VGPR round trip).
//      V LDS: no-pad [32][128] fp16 with 16B-chunk XOR swizzle (chunk ^= row&7),
//      applied by pre-swizzling the GLOBAL source address (linear DMA dest) ->
//      conflict-free f16x4 fragment reads.
//      s_setprio(1) around QK MFMA cluster. Normalize + bf16 ot write in-kernel.
// -> MFMA proj (+bias +raw-x residual), R13 form (reads bf16 ot).
//
// ws layout (bytes):
//   wq_b  bf16 49,152   @ 0
//   wp_b  bf16 16,384   @ 98,304
//   bp_f  f32  128      @ 131,072
//   gn_ab f32x2 512     @ 131,584
//   Qt    bf16 2,097,152 @ 8,388,608   [b*H+h][l][32]
//   Kt    bf16 2,097,152 @ 12,582,912  [b*H+h][l][32]
//   Vb    fp16 2,097,152 @ 16,777,216  [b*H+h][32][l]
//   ot    bf16 2,097,152 @ 20,971,520  [b][l][128]

#define B_ 4
#define C_ 128
#define L_ 4096
#define H_ 4
#define HD_ 32
#define NG_ 32
#define CPG_ 4
#define EPS_ 1e-5f
#define QKSCALE_ 0.5050097650430367f  // 32^(-1/4) * sqrt(log2 e)

typedef __attribute__((ext_vector_type(8))) short bf16x8;
typedef __attribute__((ext_vector_type(8))) unsigned short u16x8;
typedef __attribute__((ext_vector_type(4))) float f32x4;
typedef __attribute__((ext_vector_type(2))) _Float16 f16x2;
typedef __attribute__((ext_vector_type(4))) _Float16 f16x4;

#if __has_builtin(__builtin_amdgcn_exp2f)
#define EXP2F(x) __builtin_amdgcn_exp2f(x)
#else
#define EXP2F(x) exp2f(x)
#endif

// __has_builtin(amdgcn) is FALSE in the host pass but raw calls parse in device code.
// Never #error here (R11 lesson).
#define MFMA_PV(a, b, c) __builtin_amdgcn_mfma_f32_16x16x16f16((a), (b), (c), 0, 0, 0)

__device__ __forceinline__ float bu2f(unsigned short u) {
  return __builtin_bit_cast(float, (unsigned int)(((unsigned int)u) << 16));
}
__device__ __forceinline__ unsigned short f2bu(float f) {
  unsigned int u = __builtin_bit_cast(unsigned int, f);
  unsigned int r = (u + 0x7fffu + ((u >> 16) & 1u)) >> 16;  // RNE
  return (unsigned short)r;
}
__device__ __forceinline__ float4 u42f4(ushort4 u) {
  return make_float4(bu2f(u.x), bu2f(u.y), bu2f(u.z), bu2f(u.w));
}
__device__ __forceinline__ unsigned int pkbf(float a, float b) {
  return (unsigned int)f2bu(a) | ((unsigned int)f2bu(b) << 16);
}
__device__ __forceinline__ f16x2 pkhf2(float a, float b) {
#if __has_builtin(__builtin_amdgcn_cvt_pkrtz)
  return __builtin_bit_cast(f16x2, __builtin_amdgcn_cvt_pkrtz(a, b));
#else
  f16x2 r;
  r[0] = (_Float16)a;
  r[1] = (_Float16)b;
  return r;
#endif
}
__device__ __forceinline__ unsigned int pkhf(float a, float b) {
  return __builtin_bit_cast(unsigned int, pkhf2(a, b));
}

// async global->LDS DMA, 16B per lane. LDS dest must be wave-uniform base + lane*16
// (we pass per-lane base + t*16 with lane-linear t). Guide m97/m104.
__device__ __forceinline__ void gload16(const void* g, void* l) {
  __builtin_amdgcn_global_load_lds(
      (const __attribute__((address_space(1))) unsigned int*)g,
      (__attribute__((address_space(3))) unsigned int*)l, 16, 0, 0);
}

// fp32-vs-bf16 detection via wave-0 ballot — proven R9.
__device__ __forceinline__ bool detect_fast(const ushort* x) {
  __shared__ int flag_s;
  int t = threadIdx.x;
  if (t < 64) {
    int e = (x[t] >> 7) & 0xFF;
    unsigned long long m = __ballot((e < 64) || (e > 192));
    if (t == 0) flag_s = (__popcll(m) > 4) ? 1 : 0;
  }
  __syncthreads();
  return flag_s != 0;
}

__device__ __forceinline__ float4 ldx4(const void* x, size_t idx, bool f32) {
  if (f32) return *((const float4*)x + (idx >> 2));
  ushort4 u = *((const ushort4*)x + (idx >> 2));
  return u42f4(u);
}

// ---------------------------------------------------------------- GN stats + weight cvt
__global__ __launch_bounds__(256) void gn_stats(const void* __restrict__ x,
                                                const void* __restrict__ wq,
                                                const void* __restrict__ wp,
                                                const void* __restrict__ bp,
                                                const void* __restrict__ gm,
                                                const void* __restrict__ bt,
                                                ushort* __restrict__ wq_b,
                                                ushort* __restrict__ wp_b,
                                                float* __restrict__ bp_f,
                                                float2* __restrict__ gn_ab) {
  bool f32 = detect_fast((const ushort*)x);
  int blk = blockIdx.x;
  int t = threadIdx.x;

  if (blk >= 128) {
    int i0 = ((blk - 128) * 256 + t) * 8;
#pragma unroll
    for (int k = 0; k < 8; ++k) {
      int i = i0 + k;
      if (i >= 65664) break;
      if (i < 49152) {
        wq_b[i] = f32 ? f2bu(((const float*)wq)[i]) : ((const ushort*)wq)[i];
      } else if (i < 65536) {
        int off = i - 49152;
        wp_b[off] = f32 ? f2bu(((const float*)wp)[off]) : ((const ushort*)wp)[off];
      } else {
        int off = i - 65536;
        bp_f[off] = f32 ? ((const float*)bp)[off] : bu2f(((const ushort*)bp)[off]);
      }
    }
    return;
  }

  int b = blk >> 5, g = blk & 31;
  size_t base = ((size_t)b * C_ + (size_t)g * CPG_) * L_;

  float s = 0.f, ss = 0.f;
#pragma unroll
  for (int i = 0; i < 16; ++i) {
    size_t e = base + i * 1024 + t * 4;
    float4 f = ldx4(x, e, f32);
    s += f.x + f.y + f.z + f.w;
    ss += f.x * f.x + f.y * f.y + f.z * f.z + f.w * f.w;
  }
#pragma unroll
  for (int m = 32; m >= 1; m >>= 1) {
    s += __shfl_xor(s, m, 64);
    ss += __shfl_xor(ss, m, 64);
  }
  __shared__ float red[4][2];
  int wv = t >> 6;
  if ((t & 63) == 0) { red[wv][0] = s; red[wv][1] = ss; }
  __syncthreads();
  float ts = red[0][0] + red[1][0] + red[2][0] + red[3][0];
  float tss = red[0][1] + red[1][1] + red[2][1] + red[3][1];
  float mu = ts * (1.0f / 16384.0f);
  float var = tss * (1.0f / 16384.0f) - mu * mu;
  float rs = rsqrtf(var + EPS_);

  if (t < CPG_) {
    int gi = g * CPG_ + t;
    float ga = f32 ? ((const float*)gm)[gi] : bu2f(((const ushort*)gm)[gi]);
    float be = f32 ? ((const float*)bt)[gi] : bu2f(((const ushort*)bt)[gi]);
    gn_ab[b * C_ + gi] = make_float2(ga * rs, be - mu * ga * rs);
  }
}

// ---------------------------------------------------------------- QKV GEMM (MFMA, gn inline)
__global__ __launch_bounds__(256) void qkv_kernel(const ushort* __restrict__ wq_b,
                                                  const void* __restrict__ x,
                                                  const float2* __restrict__ gn_ab,
                                                  ushort* __restrict__ Qt,
                                                  ushort* __restrict__ Kt,
                                                  ushort* __restrict__ Vb) {
  bool f32 = detect_fast((const ushort*)x);
  __shared__ alignas(16) ushort Hs[64][136];
  __shared__ alignas(16) float Ls[64][69];

  int lx = blockIdx.x, oz = blockIdx.y, b = blockIdx.z;
  int t = threadIdx.x;
  int w = t >> 6, lane = t & 63, l16 = lane & 15, q = lane >> 4, q8 = q * 8;

  {
    int u = t & 63, lh = (t >> 6) * 16;
    int c0 = 2 * u;
    float2 ab0 = gn_ab[b * C_ + c0];
    float2 ab1 = gn_ab[b * C_ + c0 + 1];
    size_t xo = ((size_t)b * C_ + c0) * L_ + (size_t)lx * 64 + lh;
#pragma unroll
    for (int j = 0; j < 4; ++j) {
      float4 f0 = ldx4(x, xo + j * 4, f32);
      float4 f1 = ldx4(x, xo + L_ + j * 4, f32);
      float n0[4] = {f0.x * ab0.x + ab0.y, f0.y * ab0.x + ab0.y,
                     f0.z * ab0.x + ab0.y, f0.w * ab0.x + ab0.y};
      float n1[4] = {f1.x * ab1.x + ab1.y, f1.y * ab1.x + ab1.y,
                     f1.z * ab1.x + ab1.y, f1.w * ab1.x + ab1.y};
#pragma unroll
      for (int k = 0; k < 4; ++k)
        *(unsigned int*)&Hs[lh + j * 4 + k][c0] = pkbf(n0[k], n1[k]);
    }
  }
  __syncthreads();

  for (int j = 0; j < 2; ++j) {
    int oy = oz * 2 + j;
    const ushort* wg = wq_b + (size_t)(oy * 64 + w * 16 + l16) * C_;

    f32x4 acc[4] = {{0.f, 0.f, 0.f, 0.f}, {0.f, 0.f, 0.f, 0.f},
                    {0.f, 0.f, 0.f, 0.f}, {0.f, 0.f, 0.f, 0.f}};
#pragma unroll
    for (int kc = 0; kc < 4; ++kc) {
      bf16x8 aw = *(const bf16x8*)(wg + kc * 32 + q8);
#pragma unroll
      for (int nb = 0; nb < 4; ++nb) {
        bf16x8 bh = *(const bf16x8*)&Hs[nb * 16 + l16][kc * 32 + q8];
        acc[nb] = __builtin_amdgcn_mfma_f32_16x16x32_bf16(aw, bh, acc[nb], 0, 0, 0);
      }
    }
    __syncthreads();
#pragma unroll
    for (int nb = 0; nb < 4; ++nb)
#pragma unroll
      for (int r = 0; r < 4; ++r)
        Ls[nb * 16 + l16][w * 16 + 4 * q + r] = acc[nb][r];
    __syncthreads();

#pragma unroll
    for (int hhalf = 0; hhalf < 2; ++hhalf) {
      int hh = oy * 2 + hhalf;
      int type = hh % 3, head = hh / 3;
      size_t bh = (size_t)b * H_ + head;
      if (type == 2) {
        int c_loc = t >> 3, l8 = (t & 7) * 8;
        float v[8];
#pragma unroll
        for (int jj = 0; jj < 8; ++jj) v[jj] = Ls[l8 + jj][hhalf * 32 + c_loc];
        uint4 u;
        u.x = pkhf(v[0], v[1]);
        u.y = pkhf(v[2], v[3]);
        u.z = pkhf(v[4], v[5]);
        u.w = pkhf(v[6], v[7]);
        *(uint4*)(Vb + (bh * 32 + c_loc) * L_ + (size_t)lx * 64 + l8) = u;
      } else {
        ushort* dst = type ? Kt : Qt;
        int l = t >> 2, seg = (t & 3) * 8;
        const float* src = &Ls[l][hhalf * 32 + seg];
        uint4 u;
        u.x = pkbf(src[0] * QKSCALE_, src[1] * QKSCALE_);
        u.y = pkbf(src[2] * QKSCALE_, src[3] * QKSCALE_);
        u.z = pkbf(src[4] * QKSCALE_, src[5] * QKSCALE_);
        u.w = pkbf(src[6] * QKSCALE_, src[7] * QKSCALE_);
        *(uint4*)(dst + ((bh * L_) + lx * 64 + l) * 32 + seg) = u;
      }
    }
  }
}

// ---------------------------------------------------------------- MFMA flash attention v3
// 8 waves x 16 q-rows (128-q block). K/V via global_load_lds (16B/lane, lane-linear dest).
// V: [32][128] fp16, 16B chunks XOR-swizzled (chunk ^= row&7) via pre-swizzled global src.
// Per iter: 128 s; per wave: 8 QK MFMA (16x16x32 bf16) + 24 PV MFMA (16x16x16 f16,
// incl. ones-MFMA for l). One barrier per iter (drains DMA + LDS).
__global__ __launch_bounds__(512) void attn_kernel(const ushort* __restrict__ Qt,
                                                   const ushort* __restrict__ Kt,
                                                   const ushort* __restrict__ Vb,
                                                   ushort* __restrict__ ot) {
  __shared__ alignas(16) ushort Ks[2][4096];      // [buf][frag-linear 2x(64x32)] bf16
  __shared__ alignas(16) ushort Vs[2][32][128];   // [buf][c][s-chunks swizzled] fp16

  int t = threadIdx.x;
  int w = t >> 6, lane = t & 63, l16 = lane & 15, q = lane >> 4;
  int q8 = q * 8, q4 = q * 4;
  int trow = w * 16 + l16;
  int tq0 = blockIdx.x * 128;
  int bh = blockIdx.y;
  int b = bh >> 2, head = bh & 3;
  const ushort* Qg = Qt + ((size_t)bh * L_ + tq0) * 32;
  const ushort* Kg = Kt + (size_t)bh * L_ * 32;
  const ushort* Vg = Vb + (size_t)bh * 32 * L_;

  // K staging source: chunk i = t of frag-linear layout (two 64-s subtiles).
  {
  }
  int j = t & 255;
  int krow = ((j & 15) | ((j >> 6) << 4)) + ((t >> 8) << 6);
  int kq8s = ((j >> 4) & 3) * 8;
  const ushort* ksrc = Kg + (size_t)krow * 32 + kq8s;
  // V staging source: dest chunk t -> (row r=t>>4, phys chunk p=t&15);
  // semantic s-chunk c = (p&8) | ((p&7) ^ (r&7)).
  int vr = t >> 4, vp = t & 15;
  int vcsem = (vp & 8) | ((vp & 7) ^ (vr & 7));
  const ushort* vsrc = Vg + (size_t)vr * L_ + vcsem * 8;

  ushort* kA = (ushort*)Ks + (size_t)t * 8;
  ushort* kB = kA + 4096;
  ushort* vA = (ushort*)Vs + (size_t)t * 8;
  ushort* vB = vA + 4096;

  bf16x8 qfrag = *(const bf16x8*)(Qg + (size_t)trow * 32 + q8);
  f16x4 ones;
#pragma unroll
  for (int i = 0; i < 4; ++i) ones[i] = (_Float16)1.0f;

  // prologue: DMA tile 0 into buf A
  gload16(ksrc, kA);
  gload16(vsrc, vA);
  ksrc += 4096;
  vsrc += 128;
  __syncthreads();

  f32x4 aA = {0.f, 0.f, 0.f, 0.f};
  f32x4 aB = {0.f, 0.f, 0.f, 0.f};
  f32x4 aL = {0.f, 0.f, 0.f, 0.f};

  int flip = 0;
  for (int it = 0; it < 32; ++it) {
    if (it < 31) {
      gload16(ksrc, flip ? kA : kB);
      gload16(vsrc, flip ? vA : vB);
      ksrc += 4096;
      vsrc += 128;
    }
    const ushort* kc = (const ushort*)Ks + (flip ? 4096 : 0);
    const ushort* vc = (const ushort*)Vs + (flip ? 4096 : 0);

#pragma unroll
    for (int hh2 = 0; hh2 < 2; ++hh2) {
      const ushort* kf = kc + hh2 * 2048 + lane * 8;
      bf16x8 ak0 = *(const bf16x8*)(kf);
      bf16x8 ak1 = *(const bf16x8*)(kf + 512);
      bf16x8 ak2 = *(const bf16x8*)(kf + 1024);
      bf16x8 ak3 = *(const bf16x8*)(kf + 1536);
      f32x4 z = {0.f, 0.f, 0.f, 0.f};
      f32x4 sf[4];
      __builtin_amdgcn_s_setprio(1);
      sf[0] = __builtin_amdgcn_mfma_f32_16x16x32_bf16(ak0, qfrag, z, 0, 0, 0);
      sf[1] = __builtin_amdgcn_mfma_f32_16x16x32_bf16(ak1, qfrag, z, 0, 0, 0);
      sf[2] = __builtin_amdgcn_mfma_f32_16x16x32_bf16(ak2, qfrag, z, 0, 0, 0);
      sf[3] = __builtin_amdgcn_mfma_f32_16x16x32_bf16(ak3, qfrag, z, 0, 0, 0);
      __builtin_amdgcn_s_setprio(0);

#pragma unroll
      for (int n = 0; n < 4; ++n) {
        // V fragment: row l16 (and 16+l16), semantic f16 offset o = hh2*64+n*16+q4
        int o = hh2 * 64 + n * 16 + q4;
        int c = o >> 3;
        int pch = (c & 8) | ((c & 7) ^ (l16 & 7));
        const ushort* vrow = vc + pch * 8 + (q4 & 7);
        f16x4 va0 = *(const f16x4*)(vrow + (size_t)l16 * 128);
        f16x4 va1 = *(const f16x4*)(vrow + (size_t)(16 + l16) * 128);
        float p0 = EXP2F(sf[n][0]);
        float p1 = EXP2F(sf[n][1]);
        float p2 = EXP2F(sf[n][2]);
        float p3 = EXP2F(sf[n][3]);
        f16x2 e01 = pkhf2(p0, p1);
        f16x2 e23 = pkhf2(p2, p3);
        f16x4 pb = __builtin_shufflevector(e01, e23, 0, 1, 2, 3);
        aA = MFMA_PV(va0, pb, aA);
        aB = MFMA_PV(va1, pb, aB);
        aL = MFMA_PV(ones, pb, aL);
      }
    }
    __syncthreads();
    flip ^= 1;
  }

  // l lives in aL rows (all rows identical = l[query l16 of this wave]).
  float inv = 1.0f / aL[0];

  // epilogue: normalize, transpose O^T -> [q][c] via bf16 LDS overlay on Ks
  // (128 rows x 40 ush = 10240 B <= 16384 B), then coalesced uint4 store.
  ushort* Ep = (ushort*)Ks;
#pragma unroll
  for (int r = 0; r < 2; ++r) {
    *(unsigned int*)&Ep[trow * 40 + q4 + 2 * r] =
        pkbf(aA[2 * r] * inv, aA[2 * r + 1] * inv);
    *(unsigned int*)&Ep[trow * 40 + 16 + q4 + 2 * r] =
        pkbf(aB[2 * r] * inv, aB[2 * r + 1] * inv);
  }
  __syncthreads();
  {
    int row = t >> 2, seg = (t & 3) * 8;
    *(uint4*)(ot + ((size_t)b * L_ + tq0 + row) * C_ + head * 32 + seg) =
        *(const uint4*)&Ep[row * 40 + seg];
  }
}

// ---------------------------------------------------------------- Proj + bias + residual
// R13 form: reads bf16 ot directly.
__global__ __launch_bounds__(256) void proj_kernel(const ushort* __restrict__ wp_b,
                                                   const float* __restrict__ bias,
                                                   const void* __restrict__ x,
                                                   const ushort* __restrict__ ot,
                                                   void* __restrict__ out) {
  bool f32 = detect_fast((const ushort*)x);
  __shared__ alignas(16) float Ls[64][37];

  int lx = blockIdx.x, oy = blockIdx.y, b = blockIdx.z;
  int t = threadIdx.x;
  int w = t >> 6, lane = t & 63, l16 = lane & 15, q = lane >> 4, q8 = q * 8;

  const ushort* wg = wp_b + (size_t)(oy * 64 + w * 16 + l16) * C_;
  const ushort* og = ot + ((size_t)b * L_ + (size_t)lx * 32) * C_;

  f32x4 acc[2] = {{0.f, 0.f, 0.f, 0.f}, {0.f, 0.f, 0.f, 0.f}};
#pragma unroll
  for (int kc = 0; kc < 4; ++kc) {
    bf16x8 aw = *(const bf16x8*)(wg + kc * 32 + q8);
#pragma unroll
    for (int nb = 0; nb < 2; ++nb) {
      bf16x8 bo = *(const bf16x8*)(og + (size_t)(nb * 16 + l16) * C_ + kc * 32 + q8);
      acc[nb] = __builtin_amdgcn_mfma_f32_16x16x32_bf16(aw, bo, acc[nb], 0, 0, 0);
    }
  }
#pragma unroll
  for (int nb = 0; nb < 2; ++nb)
#pragma unroll
    for (int r = 0; r < 4; ++r)
      Ls[w * 16 + 4 * q + r][nb * 16 + l16] = acc[nb][r];
  __syncthreads();

  {
    int o_loc = t >> 2, ls0 = (t & 3) * 8;
    float bv = bias[oy * 64 + o_loc];
    size_t off = ((size_t)b * C_ + oy * 64 + o_loc) * L_ + (size_t)lx * 32 + ls0;
#pragma unroll
    for (int jj = 0; jj < 2; ++jj) {
      float4 xf = ldx4(x, off + jj * 4, f32);
      const float* sp = &Ls[o_loc][ls0 + jj * 4];
      float4 r = make_float4(sp[0] + bv + xf.x, sp[1] + bv + xf.y,
                             sp[2] + bv + xf.z, sp[3] + bv + xf.w);
      if (f32) {
        *(float4*)((float*)out + off + jj * 4) = r;
      } else {
        *(ushort4*)((ushort*)out + off + jj * 4) =
            make_ushort4(f2bu(r.x), f2bu(r.y), f2bu(r.z), f2bu(r.w));
      }
    }
  }
}

// ---------------------------------------------------------------- launch
extern "C" void kernel_launch(void* const* d_in, const int* in_sizes, int n_in,
                              void* d_out, int out_size, void* d_ws, size_t ws_size,
                              hipStream_t stream) {
  const void* x      = d_in[0];
  const void* w_qkv  = d_in[1];
  const void* w_proj = d_in[2];
  const void* b_proj = d_in[3];
  const void* gamma  = d_in[4];
  const void* beta   = d_in[5];

  char* wsb = (char*)d_ws;
  ushort* wq_b  = (ushort*)(wsb + 0);
  ushort* wp_b  = (ushort*)(wsb + 98304);
  float*  bp_f  = (float*)(wsb + 131072);
  float2* gn_ab = (float2*)(wsb + 131584);
  ushort* Qt    = (ushort*)(wsb + 8388608);
  ushort* Kt    = (ushort*)(wsb + 12582912);
  ushort* Vb    = (ushort*)(wsb + 16777216);  // fp16
  ushort* ot    = (ushort*)(wsb + 20971520);

  gn_stats<<<dim3(161), dim3(256), 0, stream>>>(x, w_qkv, w_proj, b_proj, gamma, beta,
                                                wq_b, wp_b, bp_f, gn_ab);
  qkv_kernel<<<dim3(L_ / 64, 3, B_), dim3(256), 0, stream>>>(wq_b, x, gn_ab, Qt, Kt, Vb);
  attn_kernel<<<dim3(L_ / 128, B_ * H_), dim3(512), 0, stream>>>(Qt, Kt, Vb, ot);
  proj_kernel<<<dim3(L_ / 32, C_ / 64, B_), dim3(256), 0, stream>>>(wp_b, bp_f, x, ot, d_out);
}

// Round 3
// 138.477 us; speedup vs baseline: 1.1167x; 1.0421x over previous
//
#include <hip/hip_runtime.h>
#include <hip/hip_bf16.h>
#include <cstdint>
#include <cstddef>

// B=4, C=128, L=4096, H=4 (hd=32), GROUPS=32, EPS=1e-5
// gn_stats (affine + weight cvt) -> MFMA qkv (gn inline; Qt/Kt bf16 [l][32], Vb fp16 [32][l])
// -> MFMA flash attention v4 (this round):
//      512 threads = 8 waves: 4 q-tiles(32q) x 2 s-halves(64s). 128-q block, 128 s/iter.
//      QK: mfma_f32_32x32x16_bf16 (A=K rows, B=Q cols, 2 chained for K=32).
//      PV: mfma_f32_32x32x16_f16 (A=V [c][s], B=P via permlane32_swap repack) —
//          full-rate 32x32 shape replaces the slow 16x16x16 path; ones-MFMA for l
//          replaced by v_dot2_f32_f16 on the packed P pairs.
//      K LDS [128][32] bf16 with rotation swizzle chunk=(c+row)&3; V LDS [32][128] fp16
//      with XOR swizzle chunk=(c^row&7) — both staged via global_load_lds width-16
//      with pre-swizzled global source, both giving conflict-free ds_read_b128.
//      Epilogue: s-half partials (O 32x32 f32, l) combined via padded LDS, bf16 ot.
// -> MFMA proj (+bias +raw-x residual), reads bf16 ot.
//
// ws layout (bytes):
//   wq_b  bf16 49,152   @ 0
//   wp_b  bf16 16,384   @ 98,304
//   bp_f  f32  128      @ 131,072
//   gn_ab f32x2 512     @ 131,584
//   Qt    bf16 2,097,152 @ 8,388,608   [b*H+h][l][32]
//   Kt    bf16 2,097,152 @ 12,582,912  [b*H+h][l][32]
//   Vb    fp16 2,097,152 @ 16,777,216  [b*H+h][32][l]
//   ot    bf16 2,097,152 @ 20,971,520  [b][l][128]

#define B_ 4
#define C_ 128
#define L_ 4096
#define H_ 4
#define HD_ 32
#define NG_ 32
#define CPG_ 4
#define EPS_ 1e-5f
#define QKSCALE_ 0.5050097650430367f  // 32^(-1/4) * sqrt(log2 e)

typedef __attribute__((ext_vector_type(8))) short bf16x8;
typedef __attribute__((ext_vector_type(8))) unsigned short u16x8;
typedef __attribute__((ext_vector_type(4))) float f32x4;
typedef __attribute__((ext_vector_type(16))) float f32x16;
typedef __attribute__((ext_vector_type(2))) _Float16 f16x2;
typedef __attribute__((ext_vector_type(4))) _Float16 f16x4;
typedef __attribute__((ext_vector_type(8))) _Float16 f16x8;
typedef __attribute__((ext_vector_type(2))) unsigned int u32x2;
typedef __attribute__((ext_vector_type(4))) unsigned int u32x4;

#if __has_builtin(__builtin_amdgcn_exp2f)
#define EXP2F(x) __builtin_amdgcn_exp2f(x)
#else
#define EXP2F(x) exp2f(x)
#endif

__device__ __forceinline__ float bu2f(unsigned short u) {
  return __builtin_bit_cast(float, (unsigned int)(((unsigned int)u) << 16));
}
__device__ __forceinline__ unsigned short f2bu(float f) {
  unsigned int u = __builtin_bit_cast(unsigned int, f);
  unsigned int r = (u + 0x7fffu + ((u >> 16) & 1u)) >> 16;  // RNE
  return (unsigned short)r;
}
__device__ __forceinline__ float4 u42f4(ushort4 u) {
  return make_float4(bu2f(u.x), bu2f(u.y), bu2f(u.z), bu2f(u.w));
}
__device__ __forceinline__ unsigned int pkbf(float a, float b) {
  return (unsigned int)f2bu(a) | ((unsigned int)f2bu(b) << 16);
}
__device__ __forceinline__ f16x2 pkhf2(float a, float b) {
#if __has_builtin(__builtin_amdgcn_cvt_pkrtz)
  return __builtin_bit_cast(f16x2, __builtin_amdgcn_cvt_pkrtz(a, b));
#else
  f16x2 r;
  r[0] = (_Float16)a;
  r[1] = (_Float16)b;
  return r;
#endif
}
__device__ __forceinline__ unsigned int pkhf(float a, float b) {
  return __builtin_bit_cast(unsigned int, pkhf2(a, b));
}

// async global->LDS DMA, 16B per lane. LDS dest must be wave-uniform base + lane*16.
__device__ __forceinline__ void gload16(const void* g, void* l) {
  __builtin_amdgcn_global_load_lds(
      (const __attribute__((address_space(1))) unsigned int*)g,
      (__attribute__((address_space(3))) unsigned int*)l, 16, 0, 0);
}

// fp32-vs-bf16 detection via wave-0 ballot — proven R9.
__device__ __forceinline__ bool detect_fast(const ushort* x) {
  __shared__ int flag_s;
  int t = threadIdx.x;
  if (t < 64) {
    int e = (x[t] >> 7) & 0xFF;
    unsigned long long m = __ballot((e < 64) || (e > 192));
    if (t == 0) flag_s = (__popcll(m) > 4) ? 1 : 0;
  }
  __syncthreads();
  return flag_s != 0;
}

__device__ __forceinline__ float4 ldx4(const void* x, size_t idx, bool f32) {
  if (f32) return *((const float4*)x + (idx >> 2));
  ushort4 u = *((const ushort4*)x + (idx >> 2));
  return u42f4(u);
}

// ---------------------------------------------------------------- GN stats + weight cvt
__global__ __launch_bounds__(256) void gn_stats(const void* __restrict__ x,
                                                const void* __restrict__ wq,
                                                const void* __restrict__ wp,
                                                const void* __restrict__ bp,
                                                const void* __restrict__ gm,
                                                const void* __restrict__ bt,
                                                ushort* __restrict__ wq_b,
                                                ushort* __restrict__ wp_b,
                                                float* __restrict__ bp_f,
                                                float2* __restrict__ gn_ab) {
  bool f32 = detect_fast((const ushort*)x);
  int blk = blockIdx.x;
  int t = threadIdx.x;

  if (blk >= 128) {
    int i0 = ((blk - 128) * 256 + t) * 8;
#pragma unroll
    for (int k = 0; k < 8; ++k) {
      int i = i0 + k;
      if (i >= 65664) break;
      if (i < 49152) {
        wq_b[i] = f32 ? f2bu(((const float*)wq)[i]) : ((const ushort*)wq)[i];
      } else if (i < 65536) {
        int off = i - 49152;
        wp_b[off] = f32 ? f2bu(((const float*)wp)[off]) : ((const ushort*)wp)[off];
      } else {
        int off = i - 65536;
        bp_f[off] = f32 ? ((const float*)bp)[off] : bu2f(((const ushort*)bp)[off]);
      }
    }
    return;
  }

  int b = blk >> 5, g = blk & 31;
  size_t base = ((size_t)b * C_ + (size_t)g * CPG_) * L_;

  float s = 0.f, ss = 0.f;
#pragma unroll
  for (int i = 0; i < 16; ++i) {
    size_t e = base + i * 1024 + t * 4;
    float4 f = ldx4(x, e, f32);
    s += f.x + f.y + f.z + f.w;
    ss += f.x * f.x + f.y * f.y + f.z * f.z + f.w * f.w;
  }
#pragma unroll
  for (int m = 32; m >= 1; m >>= 1) {
    s += __shfl_xor(s, m, 64);
    ss += __shfl_xor(ss, m, 64);
  }
  __shared__ float red[4][2];
  int wv = t >> 6;
  if ((t & 63) == 0) { red[wv][0] = s; red[wv][1] = ss; }
  __syncthreads();
  float ts = red[0][0] + red[1][0] + red[2][0] + red[3][0];
  float tss = red[0][1] + red[1][1] + red[2][1] + red[3][1];
  float mu = ts * (1.0f / 16384.0f);
  float var = tss * (1.0f / 16384.0f) - mu * mu;
  float rs = rsqrtf(var + EPS_);

  if (t < CPG_) {
    int gi = g * CPG_ + t;
    float ga = f32 ? ((const float*)gm)[gi] : bu2f(((const ushort*)gm)[gi]);
    float be = f32 ? ((const float*)bt)[gi] : bu2f(((const ushort*)bt)[gi]);
    gn_ab[b * C_ + gi] = make_float2(ga * rs, be - mu * ga * rs);
  }
}

// ---------------------------------------------------------------- QKV GEMM (MFMA, gn inline)
__global__ __launch_bounds__(256) void qkv_kernel(const ushort* __restrict__ wq_b,
                                                  const void* __restrict__ x,
                                                  const float2* __restrict__ gn_ab,
                                                  ushort* __restrict__ Qt,
                                                  ushort* __restrict__ Kt,
                                                  ushort* __restrict__ Vb) {
  bool f32 = detect_fast((const ushort*)x);
  __shared__ alignas(16) ushort Hs[64][136];
  __shared__ alignas(16) float Ls[64][69];

  int lx = blockIdx.x, oz = blockIdx.y, b = blockIdx.z;
  int t = threadIdx.x;
  int w = t >> 6, lane = t & 63, l16 = lane & 15, q = lane >> 4, q8 = q * 8;

  {
    int u = t & 63, lh = (t >> 6) * 16;
    int c0 = 2 * u;
    float2 ab0 = gn_ab[b * C_ + c0];
    float2 ab1 = gn_ab[b * C_ + c0 + 1];
    size_t xo = ((size_t)b * C_ + c0) * L_ + (size_t)lx * 64 + lh;
#pragma unroll
    for (int j = 0; j < 4; ++j) {
      float4 f0 = ldx4(x, xo + j * 4, f32);
      float4 f1 = ldx4(x, xo + L_ + j * 4, f32);
      float n0[4] = {f0.x * ab0.x + ab0.y, f0.y * ab0.x + ab0.y,
                     f0.z * ab0.x + ab0.y, f0.w * ab0.x + ab0.y};
      float n1[4] = {f1.x * ab1.x + ab1.y, f1.y * ab1.x + ab1.y,
                     f1.z * ab1.x + ab1.y, f1.w * ab1.x + ab1.y};
#pragma unroll
      for (int k = 0; k < 4; ++k)
        *(unsigned int*)&Hs[lh + j * 4 + k][c0] = pkbf(n0[k], n1[k]);
    }
  }
  __syncthreads();

  for (int j = 0; j < 2; ++j) {
    int oy = oz * 2 + j;
    const ushort* wg = wq_b + (size_t)(oy * 64 + w * 16 + l16) * C_;

    f32x4 acc[4] = {{0.f, 0.f, 0.f, 0.f}, {0.f, 0.f, 0.f, 0.f},
                    {0.f, 0.f, 0.f, 0.f}, {0.f, 0.f, 0.f, 0.f}};
#pragma unroll
    for (int kc = 0; kc < 4; ++kc) {
      bf16x8 aw = *(const bf16x8*)(wg + kc * 32 + q8);
#pragma unroll
      for (int nb = 0; nb < 4; ++nb) {
        bf16x8 bh = *(const bf16x8*)&Hs[nb * 16 + l16][kc * 32 + q8];
        acc[nb] = __builtin_amdgcn_mfma_f32_16x16x32_bf16(aw, bh, acc[nb], 0, 0, 0);
      }
    }
    __syncthreads();
#pragma unroll
    for (int nb = 0; nb < 4; ++nb)
#pragma unroll
      for (int r = 0; r < 4; ++r)
        Ls[nb * 16 + l16][w * 16 + 4 * q + r] = acc[nb][r];
    __syncthreads();

#pragma unroll
    for (int hhalf = 0; hhalf < 2; ++hhalf) {
      int hh = oy * 2 + hhalf;
      int type = hh % 3, head = hh / 3;
      size_t bh = (size_t)b * H_ + head;
      if (type == 2) {
        int c_loc = t >> 3, l8 = (t & 7) * 8;
        float v[8];
#pragma unroll
        for (int jj = 0; jj < 8; ++jj) v[jj] = Ls[l8 + jj][hhalf * 32 + c_loc];
        uint4 u;
        u.x = pkhf(v[0], v[1]);
        u.y = pkhf(v[2], v[3]);
        u.z = pkhf(v[4], v[5]);
        u.w = pkhf(v[6], v[7]);
        *(uint4*)(Vb + (bh * 32 + c_loc) * L_ + (size_t)lx * 64 + l8) = u;
      } else {
        ushort* dst = type ? Kt : Qt;
        int l = t >> 2, seg = (t & 3) * 8;
        const float* src = &Ls[l][hhalf * 32 + seg];
        uint4 u;
        u.x = pkbf(src[0] * QKSCALE_, src[1] * QKSCALE_);
        u.y = pkbf(src[2] * QKSCALE_, src[3] * QKSCALE_);
        u.z = pkbf(src[4] * QKSCALE_, src[5] * QKSCALE_);
        u.w = pkbf(src[6] * QKSCALE_, src[7] * QKSCALE_);
        *(uint4*)(dst + ((bh * L_) + lx * 64 + l) * 32 + seg) = u;
      }
    }
  }
}

// ---------------------------------------------------------------- MFMA flash attention v4
// Wave w: qt = w&3 (32-q tile), sh = w>>2 (64-s half of the 128-s iter tile).
// K LDS: [128 s][4 chunks of 16B], chunk rotated by row: pos = (c_sem + row)&3.
// V LDS: [32 c][16 chunks of 16B], chunk XORed: pos = (c&8)|((c&7)^(row&7)).
// Both staged linearly by DMA from pre-swizzled global addresses.
__global__ __launch_bounds__(512, 6) void attn_kernel(const ushort* __restrict__ Qt,
                                                      const ushort* __restrict__ Kt,
                                                      const ushort* __restrict__ Vb,
                                                      ushort* __restrict__ ot) {
  // [0,16384): K 2 bufs x 8192B ; [16384,32768): V 2 bufs x 8192B
  // epilogue overlay: Osh [8][32][33] f32 = 33792B ; Lp [4][128] f32 @ 33792
  __shared__ alignas(16) char smem[35840];

  int t = threadIdx.x;
  int w = t >> 6, lane = t & 63, l31 = lane & 31, hi = lane >> 5;
  int qt = w & 3, sh = w >> 2;
  int tq0 = blockIdx.x * 128;
  int bh = blockIdx.y;
  int b = bh >> 2, head = bh & 3;
  const ushort* Qg = Qt + ((size_t)bh * L_ + tq0) * 32;
  const ushort* Kg = Kt + (size_t)bh * L_ * 32;
  const ushort* Vg = Vb + (size_t)bh * 32 * L_;

  // staging sources (pre-swizzled so linear DMA dest yields swizzled LDS)
  int rd = t >> 2, pd = t & 3;
  int kcsem = (pd - rd) & 3;
  const ushort* ksrc = Kg + (size_t)rd * 32 + kcsem * 8;
  int vr = t >> 4, vp = t & 15;
  int vcsem = (vp & 8) | ((vp & 7) ^ (vr & 7));
  const ushort* vsrc = Vg + (size_t)vr * L_ + vcsem * 8;

  char* kb0 = smem;
  char* kb1 = smem + 8192;
  char* vb0 = smem + 16384;
  char* vb1 = smem + 24576;

  // Q fragments (B operand): lane holds Q[q=qt*32+l31][k = 8*hi + j] (+16 for second K-half)
  const ushort* qbase = Qg + (size_t)(qt * 32 + l31) * 32;
  bf16x8 qB0 = *(const bf16x8*)(qbase + 8 * hi);
  bf16x8 qB1 = *(const bf16x8*)(qbase + 16 + 8 * hi);

  const f16x2 one2 = {(_Float16)1.0f, (_Float16)1.0f};

  // prologue: DMA tile 0 into buf A
  gload16(ksrc, kb0 + (size_t)t * 16);
  gload16(vsrc, vb0 + (size_t)t * 16);
  ksrc += 4096;
  vsrc += 128;
  __syncthreads();

  f32x16 aO = {0.f};
  float lsum = 0.f;

  int flip = 0;
  for (int it = 0; it < 32; ++it) {
    if (it < 31) {
      gload16(ksrc, (flip ? kb0 : kb1) + (size_t)t * 16);
      gload16(vsrc, (flip ? vb0 : vb1) + (size_t)t * 16);
      ksrc += 4096;
      vsrc += 128;
    }
    const ushort* kc = (const ushort*)(flip ? kb1 : kb0);
    const ushort* vc = (const ushort*)(flip ? vb1 : vb0);

#pragma unroll
    for (int st = 0; st < 2; ++st) {
      int s0 = 64 * sh + 32 * st;
      const ushort* krow = kc + (size_t)(s0 + l31) * 32;
      bf16x8 aK0 = *(const bf16x8*)(krow + ((hi + l31) & 3) * 8);
      bf16x8 aK1 = *(const bf16x8*)(krow + ((2 + hi + l31) & 3) * 8);
      f32x16 zz = {0.f};
      f32x16 sf;
      __builtin_amdgcn_s_setprio(1);
      sf = __builtin_amdgcn_mfma_f32_32x32x16_bf16(aK0, qB0, zz, 0, 0, 0);
      sf = __builtin_amdgcn_mfma_f32_32x32x16_bf16(aK1, qB1, sf, 0, 0, 0);
      __builtin_amdgcn_s_setprio(0);

#pragma unroll
      for (int sb = 0; sb < 2; ++sb) {
        int sblk = 4 * sh + 2 * st + sb;
        // V fragment (A operand): V[c=l31][s = sblk*16 + 8*hi + j]
        int kci = 2 * sblk + hi;
        int vpos = (kci & 8) | ((kci & 7) ^ (l31 & 7));
        f16x8 vf = *(const f16x8*)(vc + (size_t)l31 * 128 + vpos * 8);

        float p0 = EXP2F(sf[8 * sb + 0]);
        float p1 = EXP2F(sf[8 * sb + 1]);
        float p2 = EXP2F(sf[8 * sb + 2]);
        float p3 = EXP2F(sf[8 * sb + 3]);
        float p4 = EXP2F(sf[8 * sb + 4]);
        float p5 = EXP2F(sf[8 * sb + 5]);
        float p6 = EXP2F(sf[8 * sb + 6]);
        float p7 = EXP2F(sf[8 * sb + 7]);
        f16x2 cA0 = pkhf2(p0, p1), cA1 = pkhf2(p2, p3);
        f16x2 cB0 = pkhf2(p4, p5), cB1 = pkhf2(p6, p7);
        lsum = __builtin_amdgcn_fdot2(cA0, one2, lsum, false);
        lsum = __builtin_amdgcn_fdot2(cA1, one2, lsum, false);
        lsum = __builtin_amdgcn_fdot2(cB0, one2, lsum, false);
        lsum = __builtin_amdgcn_fdot2(cB1, one2, lsum, false);

        // B-fragment repack: (w0,w2) = swap(qA.x, qB.x); (w1,w3) = swap(qA.y, qB.y)
        u32x2 r0 = __builtin_amdgcn_permlane32_swap(
            __builtin_bit_cast(unsigned int, cA0),
            __builtin_bit_cast(unsigned int, cB0), false, false);
        u32x2 r1 = __builtin_amdgcn_permlane32_swap(
            __builtin_bit_cast(unsigned int, cA1),
            __builtin_bit_cast(unsigned int, cB1), false, false);
        u32x4 pw = {r0.x, r1.x, r0.y, r1.y};
        f16x8 pf = __builtin_bit_cast(f16x8, pw);

        __builtin_amdgcn_s_setprio(1);
        aO = __builtin_amdgcn_mfma_f32_32x32x16_f16(vf, pf, aO, 0, 0, 0);
        __builtin_amdgcn_s_setprio(0);
      }
    }
    __syncthreads();
    flip ^= 1;
  }

  // ---- epilogue: write partials (padded rows: bank = (l31 + c) % 32, conflict-free)
  float* Osh = (float*)smem;                // [slot=sh*4+qt][q=32][c=33pad]
  float* Lp = (float*)(smem + 33792);       // [sh*2+hi][128]
  {
    float* ob = Osh + (size_t)(sh * 4 + qt) * (32 * 33) + (size_t)l31 * 33;
#pragma unroll
    for (int reg = 0; reg < 16; ++reg) {
      int R = (reg & 3) + 8 * (reg >> 2) + 4 * hi;
      ob[R] = aO[reg];
    }
    Lp[(sh * 2 + hi) * 128 + qt * 32 + l31] = lsum;
  }
  __syncthreads();

  // combine s-halves + hi-halves, normalize, pack bf16, coalesced store
  {
    int qloc = t >> 2, c0 = (t & 3) * 8;
    int qt2 = qloc >> 5, q31 = qloc & 31;
    float lt = Lp[qloc] + Lp[128 + qloc] + Lp[256 + qloc] + Lp[384 + qloc];
    float inv = 1.0f / lt;
    const float* o0 = Osh + (size_t)qt2 * (32 * 33) + (size_t)q31 * 33 + c0;
    const float* o1 = o0 + 4 * (32 * 33);
    float o[8];
#pragma unroll
    for (int jj = 0; jj < 8; ++jj) o[jj] = (o0[jj] + o1[jj]) * inv;
    uint4 u;
    u.x = pkbf(o[0], o[1]);
    u.y = pkbf(o[2], o[3]);
    u.z = pkbf(o[4], o[5]);
    u.w = pkbf(o[6], o[7]);
    *(uint4*)(ot + ((size_t)b * L_ + tq0 + qloc) * C_ + head * 32 + c0) = u;
  }
}

// ---------------------------------------------------------------- Proj + bias + residual
__global__ __launch_bounds__(256) void proj_kernel(const ushort* __restrict__ wp_b,
                                                   const float* __restrict__ bias,
                                                   const void* __restrict__ x,
                                                   const ushort* __restrict__ ot,
                                                   void* __restrict__ out) {
  bool f32 = detect_fast((const ushort*)x);
  __shared__ alignas(16) float Ls[64][37];

  int lx = blockIdx.x, oy = blockIdx.y, b = blockIdx.z;
  int t = threadIdx.x;
  int w = t >> 6, lane = t & 63, l16 = lane & 15, q = lane >> 4, q8 = q * 8;

  const ushort* wg = wp_b + (size_t)(oy * 64 + w * 16 + l16) * C_;
  const ushort* og = ot + ((size_t)b * L_ + (size_t)lx * 32) * C_;

  f32x4 acc[2] = {{0.f, 0.f, 0.f, 0.f}, {0.f, 0.f, 0.f, 0.f}};
#pragma unroll
  for (int kc = 0; kc < 4; ++kc) {
    bf16x8 aw = *(const bf16x8*)(wg + kc * 32 + q8);
#pragma unroll
    for (int nb = 0; nb < 2; ++nb) {
      bf16x8 bo = *(const bf16x8*)(og + (size_t)(nb * 16 + l16) * C_ + kc * 32 + q8);
      acc[nb] = __builtin_amdgcn_mfma_f32_16x16x32_bf16(aw, bo, acc[nb], 0, 0, 0);
    }
  }
#pragma unroll
  for (int nb = 0; nb < 2; ++nb)
#pragma unroll
    for (int r = 0; r < 4; ++r)
      Ls[w * 16 + 4 * q + r][nb * 16 + l16] = acc[nb][r];
  __syncthreads();

  {
    int o_loc = t >> 2, ls0 = (t & 3) * 8;
    float bv = bias[oy * 64 + o_loc];
    size_t off = ((size_t)b * C_ + oy * 64 + o_loc) * L_ + (size_t)lx * 32 + ls0;
#pragma unroll
    for (int jj = 0; jj < 2; ++jj) {
      float4 xf = ldx4(x, off + jj * 4, f32);
      const float* sp = &Ls[o_loc][ls0 + jj * 4];
      float4 r = make_float4(sp[0] + bv + xf.x, sp[1] + bv + xf.y,
                             sp[2] + bv + xf.z, sp[3] + bv + xf.w);
      if (f32) {
        *(float4*)((float*)out + off + jj * 4) = r;
      } else {
        *(ushort4*)((ushort*)out + off + jj * 4) =
            make_ushort4(f2bu(r.x), f2bu(r.y), f2bu(r.z), f2bu(r.w));
      }
    }
  }
}

// ---------------------------------------------------------------- launch
extern "C" void kernel_launch(void* const* d_in, const int* in_sizes, int n_in,
                              void* d_out, int out_size, void* d_ws, size_t ws_size,
                              hipStream_t stream) {
  const void* x      = d_in[0];
  const void* w_qkv  = d_in[1];
  const void* w_proj = d_in[2];
  const void* b_proj = d_in[3];
  const void* gamma  = d_in[4];
  const void* beta   = d_in[5];

  char* wsb = (char*)d_ws;
  ushort* wq_b  = (ushort*)(wsb + 0);
  ushort* wp_b  = (ushort*)(wsb + 98304);
  float*  bp_f  = (float*)(wsb + 131072);
  float2* gn_ab = (float2*)(wsb + 131584);
  ushort* Qt    = (ushort*)(wsb + 8388608);
  ushort* Kt    = (ushort*)(wsb + 12582912);
  ushort* Vb    = (ushort*)(wsb + 16777216);  // fp16
  ushort* ot    = (ushort*)(wsb + 20971520);

  gn_stats<<<dim3(161), dim3(256), 0, stream>>>(x, w_qkv, w_proj, b_proj, gamma, beta,
                                                wq_b, wp_b, bp_f, gn_ab);
  qkv_kernel<<<dim3(L_ / 64, 3, B_), dim3(256), 0, stream>>>(wq_b, x, gn_ab, Qt, Kt, Vb);
  attn_kernel<<<dim3(L_ / 128, B_ * H_), dim3(512), 0, stream>>>(Qt, Kt, Vb, ot);
  proj_kernel<<<dim3(L_ / 32, C_ / 64, B_), dim3(256), 0, stream>>>(wp_b, bp_f, x, ot, d_out);
}